// Round 4
// baseline (390.115 us; speedup 1.0000x reference)
//
#include <hip/hip_runtime.h>
#include <hip/hip_bf16.h>

// out[s,b,o] = sum_h in[s,b,h] * w[o,h]
// A = [M=8192, K=1024] fp32, W = [N=4096, K=1024] fp32 (B^T layout), C = [M,N] fp32.
// R1->R2: XOR-swizzled LDS (conflicts 2.5e7 -> 0), 115 -> 101 us.
// R3: K-phase stagger REGRESSED (FETCH 82->143 MB, L2 locality loss). Reverted.
// R3->R4: barrier-free direct-register GEMM. MfmaUtil==MFMA-floor showed all
// excess time is the per-iter vmcnt(0)+barrier drain + LDS round-trip. Inputs
// are L2/L3-resident (25 MB bf16 total), so fragments are loaded straight
// from global to VGPRs (same addresses the LDS reads produced in R2), with a
// cur/nxt software prefetch. No __syncthreads, no LDS in the main loop.

typedef __bf16 bf16x8_t __attribute__((ext_vector_type(8)));
typedef float f32x4_t __attribute__((ext_vector_type(4)));

constexpr int M = 8192;
constexpr int N = 4096;
constexpr int K = 1024;
constexpr int BM = 128;
constexpr int BN = 128;

// ---------------- fp32 -> bf16 convert, both tensors in one launch ----------
__global__ __launch_bounds__(256) void cvt_f32_bf16(const float* __restrict__ a,
                                                    const float* __restrict__ w,
                                                    __bf16* __restrict__ a_bf,
                                                    __bf16* __restrict__ w_bf) {
    size_t i = ((size_t)blockIdx.x * 256 + threadIdx.x) * 8;
    const float* src;
    __bf16* dst;
    if (i < (size_t)M * K) {
        src = a + i;
        dst = a_bf + i;
    } else {
        size_t j = i - (size_t)M * K;
        src = w + j;
        dst = w_bf + j;
    }
    float4 v0 = *(const float4*)(src);
    float4 v1 = *(const float4*)(src + 4);
    bf16x8_t o;
    o[0] = (__bf16)v0.x; o[1] = (__bf16)v0.y; o[2] = (__bf16)v0.z; o[3] = (__bf16)v0.w;
    o[4] = (__bf16)v1.x; o[5] = (__bf16)v1.y; o[6] = (__bf16)v1.z; o[7] = (__bf16)v1.w;
    *(bf16x8_t*)dst = o;
}

// ---------------- bf16 GEMM, B^T input, direct-register (no LDS) ------------
__global__ __launch_bounds__(256) void gemm_bt(const __bf16* __restrict__ A,
                                               const __bf16* __restrict__ B,
                                               float* __restrict__ C) {
    const int tid = threadIdx.x;
    const int lane = tid & 63;
    const int wave = tid >> 6;       // 4 waves, 2x2 grid of 64x64 wave-tiles
    const int wr = wave >> 1;
    const int wc = wave & 1;
    const int quad = lane >> 4;      // 0..3
    const int l16 = lane & 15;       // 0..15

    const int bm = blockIdx.y * BM;
    const int bn = blockIdx.x * BN;

    // Fragment source pointers (fixed; only the k-offset advances).
    // A-frag for mfma_16x16x32: lane holds A[m = l16][k = quad*8 + j], j=0..7.
    // B-frag symmetric: lane holds B^T-row (= output col) l16, same k chunk.
    const __bf16* pa[4];
    const __bf16* pb[4];
#pragma unroll
    for (int i = 0; i < 4; ++i)
        pa[i] = A + (size_t)(bm + wr * 64 + i * 16 + l16) * K + quad * 8;
#pragma unroll
    for (int j = 0; j < 4; ++j)
        pb[j] = B + (size_t)(bn + wc * 64 + j * 16 + l16) * K + quad * 8;

    f32x4_t acc[4][4] = {};

    bf16x8_t a_cur[4], b_cur[4], a_nxt[4], b_nxt[4];
#pragma unroll
    for (int i = 0; i < 4; ++i) a_cur[i] = *(const bf16x8_t*)(pa[i]);
#pragma unroll
    for (int j = 0; j < 4; ++j) b_cur[j] = *(const bf16x8_t*)(pb[j]);

    for (int kk = 0; kk < K; kk += 32) {
        // Prefetch next k-step (wraps to 0 on the last iter: valid addr, unused).
        const int kn = (kk + 32) & (K - 1);
#pragma unroll
        for (int i = 0; i < 4; ++i) a_nxt[i] = *(const bf16x8_t*)(pa[i] + kn);
#pragma unroll
        for (int j = 0; j < 4; ++j) b_nxt[j] = *(const bf16x8_t*)(pb[j] + kn);

#pragma unroll
        for (int i = 0; i < 4; ++i)
#pragma unroll
            for (int j = 0; j < 4; ++j)
                acc[i][j] = __builtin_amdgcn_mfma_f32_16x16x32_bf16(a_cur[i], b_cur[j], acc[i][j], 0, 0, 0);

#pragma unroll
        for (int i = 0; i < 4; ++i) a_cur[i] = a_nxt[i];
#pragma unroll
        for (int j = 0; j < 4; ++j) b_cur[j] = b_nxt[j];
    }

    // C/D layout (verified m89/m91): col = lane&15, row = quad*4 + reg.
    // Nontemporal: C is write-once; keep it out of L2/L3 so A/W stay resident.
    const int crow0 = bm + wr * 64 + quad * 4;
    const int ccol0 = bn + wc * 64 + l16;
#pragma unroll
    for (int i = 0; i < 4; ++i)
#pragma unroll
        for (int j = 0; j < 4; ++j)
#pragma unroll
            for (int r = 0; r < 4; ++r)
                __builtin_nontemporal_store(acc[i][j][r],
                    &C[(size_t)(crow0 + i * 16 + r) * N + (ccol0 + j * 16)]);
}

extern "C" void kernel_launch(void* const* d_in, const int* in_sizes, int n_in,
                              void* d_out, int out_size, void* d_ws, size_t ws_size,
                              hipStream_t stream) {
    const float* in_f32 = (const float*)d_in[0];   // [M,K]
    const float* w_f32  = (const float*)d_in[1];   // [N,K]
    float* out = (float*)d_out;                     // [M,N]

    __bf16* A_bf = (__bf16*)d_ws;
    __bf16* W_bf = A_bf + (size_t)M * K;

    cvt_f32_bf16<<<((size_t)(M + N) * K) / (8 * 256), 256, 0, stream>>>(in_f32, w_f32, A_bf, W_bf);

    dim3 grid(N / BN, M / BM);   // (32, 64) = 2048 blocks
    gemm_bt<<<grid, 256, 0, stream>>>(A_bf, W_bf, out);
}